// Round 9
// baseline (18818.974 us; speedup 1.0000x reference)
//
#include <hip/hip_runtime.h>
#include <hip/hip_bf16.h>

#define NPTS 16384
#define MCENT 4096
#define BCLD 2
#define FDIM 32
#define H1DIM 64
#define CODIM 128
#define KNBR 64
// largest fp32 <= 0.04 (float64) == fp32(0.04f) == 0.039999999105930328
#define R2CUT 0.04f

// Exact (numpy-order, contraction-free) squared distance: ((dx*dx+dy*dy)+dz*dz)
__device__ __forceinline__ float d2e(float ax, float ay, float az,
                                     float bx, float by, float bz) {
  float dx = __fsub_rn(ax, bx);
  float dy = __fsub_rn(ay, by);
  float dz = __fsub_rn(az, bz);
  return __fadd_rn(__fadd_rn(__fmul_rn(dx, dx), __fmul_rn(dy, dy)), __fmul_rn(dz, dz));
}

// 3-bit spread for 9-bit Morton
__device__ __forceinline__ int spread3(int v) {
  return ((v & 4) << 4) | ((v & 2) << 2) | (v & 1);
}
__device__ __forceinline__ int cell_of(float x, float y, float z) {
  int cx = min(7, (int)(x * 8.0f));
  int cy = min(7, (int)(y * 8.0f));
  int cz = min(7, (int)(z * 8.0f));
  return (spread3(cx) << 2) | (spread3(cy) << 1) | spread3(cz);
}

// Lexicographic max over (hi,lo) u32 pairs via DPP (VALU pipe — no LDS).
// Identity (0,0) can never beat a real candidate (real lo = ~idx > 0).
#define DPP_LEXMAX_STEP(bb, nn, ctrl)                                          \
  do {                                                                         \
    unsigned _ob = (unsigned)__builtin_amdgcn_update_dpp(0, (int)(bb), ctrl,   \
                                                         0xf, 0xf, false);     \
    unsigned _on = (unsigned)__builtin_amdgcn_update_dpp(0, (int)(nn), ctrl,   \
                                                         0xf, 0xf, false);     \
    bool _t = (_ob > (bb)) || (_ob == (bb) && _on > (nn));                     \
    (bb) = _t ? _ob : (bb);                                                    \
    (nn) = _t ? _on : (nn);                                                    \
  } while (0)

#define DPP_LEXMAX_FULL(bb, nn)                                                \
  do {                                                                         \
    DPP_LEXMAX_STEP(bb, nn, 0x111); /* row_shr:1  */                           \
    DPP_LEXMAX_STEP(bb, nn, 0x112); /* row_shr:2  */                           \
    DPP_LEXMAX_STEP(bb, nn, 0x114); /* row_shr:4  */                           \
    DPP_LEXMAX_STEP(bb, nn, 0x118); /* row_shr:8  */                           \
    DPP_LEXMAX_STEP(bb, nn, 0x142); /* row_bcast:15 */                         \
    DPP_LEXMAX_STEP(bb, nn, 0x143); /* row_bcast:31 -> lane63 has wave max */  \
  } while (0)

__device__ __forceinline__ int rdlane(int v, int l) {
  return __builtin_amdgcn_readlane(v, l);
}
__device__ __forceinline__ float rdlanef(float v, int l) {
  return __int_as_float(__builtin_amdgcn_readlane(__float_as_int(v), l));
}

// -------- Kernel 0: Morton counting sort + per-sub (128-pt) meta precompute --
// (parallel, 2 x 1024 threads; runs once before the serial FPS wave)
__global__ __launch_bounds__(1024) void sort_kernel(const float* __restrict__ pos,
                                                    float4* __restrict__ Sall,
                                                    unsigned* __restrict__ umeta,
                                                    float* __restrict__ fmeta) {
  const int b = blockIdx.x;
  const float* P = pos + (size_t)b * NPTS * 3;
  float4* S = Sall + (size_t)b * NPTS;
  const int tid = threadIdx.x;

  __shared__ int hist[512];
  __shared__ int offs[512];

  if (tid < 512) hist[tid] = 0;
  __syncthreads();
#pragma unroll 4
  for (int j = 0; j < 16; ++j) {
    int i = tid + j * 1024;
    float x = P[3 * i + 0], y = P[3 * i + 1], z = P[3 * i + 2];
    atomicAdd(&hist[cell_of(x, y, z)], 1);
  }
  __syncthreads();
  if (tid < 64) {  // wave 0: exclusive scan of 512 cells
    int base = tid * 8;
    int loc[8];
    int run = 0;
#pragma unroll
    for (int k = 0; k < 8; ++k) { loc[k] = run; run += hist[base + k]; }
    int inc = run;
#pragma unroll
    for (int off = 1; off < 64; off <<= 1) {
      int o = __shfl_up(inc, off);
      if (tid >= off) inc += o;
    }
    int ex = inc - run;
#pragma unroll
    for (int k = 0; k < 8; ++k) offs[base + k] = ex + loc[k];
  }
  __syncthreads();
#pragma unroll 4
  for (int j = 0; j < 16; ++j) {
    int i = tid + j * 1024;
    float x = P[3 * i + 0], y = P[3 * i + 1], z = P[3 * i + 2];
    int p = atomicAdd(&offs[cell_of(x, y, z)], 1);
    S[p] = make_float4(x, y, z, __int_as_float(i));
  }
  __syncthreads();  // S writes drained/visible block-wide (validated R2-R8)

  // per-sub meta: sub s = S[s*128 .. s*128+127]; initial d vs original point 0
  if (tid < 128) {
    const float x0 = P[0], y0 = P[1], z0 = P[2];
    unsigned kb = 0u, kn = 0u;
    float bpx = 0.f, bpy = 0.f, bpz = 0.f;
    float xm = 1e30f, xM = -1e30f, ym = 1e30f, yM = -1e30f, zm = 1e30f, zM = -1e30f;
    const float4* Ss = S + tid * 128;
    for (int t = 0; t < 128; ++t) {
      float4 v = Ss[t];
      float dj = d2e(v.x, v.y, v.z, x0, y0, z0);
      xm = fminf(xm, v.x); xM = fmaxf(xM, v.x);
      ym = fminf(ym, v.y); yM = fmaxf(yM, v.y);
      zm = fminf(zm, v.z); zM = fmaxf(zM, v.z);
      unsigned db = __float_as_uint(dj);
      unsigned nj = ~(unsigned)__float_as_int(v.w);
      bool g = (db > kb) || (db == kb && nj > kn);
      kb = g ? db : kb; kn = g ? nj : kn;
      bpx = g ? v.x : bpx; bpy = g ? v.y : bpy; bpz = g ? v.z : bpz;
    }
    const int gi = b * 128 + tid;
    umeta[0 * 256 + gi] = kb;
    umeta[1 * 256 + gi] = kn;
    fmeta[0 * 256 + gi] = bpx;
    fmeta[1 * 256 + gi] = bpy;
    fmeta[2 * 256 + gi] = bpz;
    fmeta[3 * 256 + gi] = xm;
    fmeta[4 * 256 + gi] = xM;
    fmeta[5 * 256 + gi] = ym;
    fmeta[6 * 256 + gi] = yM;
    fmeta[7 * 256 + gi] = zm;
    fmeta[8 * 256 + gi] = zM;
  }
}

// ---------------- Kernel 1: single-wave FPS (1 wave per cloud) -------------
// No barriers, no LDS mailbox, no cross-wave combine — the block-wide argmax
// of R1-R8 (its ~4000 cyc/iter machinery floor) becomes one 6-step DPP lexmax.
// d[16384] lives in LDS (64 KB; lane touches only indices == lane mod 64 —
// zero intra-wave hazards). 128 Morton subs of 128 pts; per-lane meta for 2
// subs (bbox prune, 0.999 margin >> fp rounding); dirty subs updated
// cooperatively by all 64 lanes (2 pts/lane) with positions re-read from the
// L2-resident sorted S. 1 wave/SIMD => up to 512 VGPRs: no spill/AGPR risk
// (R5/R7/R8 failure modes). Selection sequence bit-identical to ref.
__global__ __launch_bounds__(64) void fps_wave(const float* __restrict__ pos,
                                               int* __restrict__ fps_idx,
                                               const float4* __restrict__ Sall,
                                               const unsigned* __restrict__ umeta,
                                               const float* __restrict__ fmeta) {
  const int b = blockIdx.x;
  const int lane = threadIdx.x;
  const float* P = pos + (size_t)b * NPTS * 3;
  const float4* Sb = Sall + (size_t)b * NPTS;

  __shared__ float dL[NPTS];  // 64 KB

  const float x0 = P[0], y0 = P[1], z0 = P[2];
#pragma unroll 4
  for (int it = 0; it < 256; ++it) {
    int i = it * 64 + lane;
    float4 v = Sb[i];
    dL[i] = d2e(v.x, v.y, v.z, x0, y0, z0);
  }

  // my 2 subs' meta (sub = lane*2 + s2)
  unsigned skb[2], skn[2];
  float spx[2], spy[2], spz[2];
  float bxm[2], bxM[2], bym[2], byM[2], bzm[2], bzM[2];
#pragma unroll
  for (int s2 = 0; s2 < 2; ++s2) {
    const int gi = b * 128 + lane * 2 + s2;
    skb[s2] = umeta[0 * 256 + gi];
    skn[s2] = umeta[1 * 256 + gi];
    spx[s2] = fmeta[0 * 256 + gi];
    spy[s2] = fmeta[1 * 256 + gi];
    spz[s2] = fmeta[2 * 256 + gi];
    bxm[s2] = fmeta[3 * 256 + gi];
    bxM[s2] = fmeta[4 * 256 + gi];
    bym[s2] = fmeta[5 * 256 + gi];
    byM[s2] = fmeta[6 * 256 + gi];
    bzm[s2] = fmeta[7 * 256 + gi];
    bzM[s2] = fmeta[8 * 256 + gi];
  }

  if (lane == 0) fps_idx[b * MCENT] = 0;

  for (int m = 1; m < MCENT; ++m) {
    // lane key = lexmax of my 2 sub keys (with best-pos carried)
    bool g2 = (skb[1] > skb[0]) || (skb[1] == skb[0] && skn[1] > skn[0]);
    unsigned lkb = g2 ? skb[1] : skb[0];
    unsigned lkn = g2 ? skn[1] : skn[0];
    float lpx = g2 ? spx[1] : spx[0];
    float lpy = g2 ? spy[1] : spy[0];
    float lpz = g2 ? spz[1] : spz[0];

    unsigned bb = lkb, nn = lkn;
    DPP_LEXMAX_FULL(bb, nn);
    const unsigned Whi = (unsigned)rdlane((int)bb, 63);
    const unsigned Wlo = (unsigned)rdlane((int)nn, 63);
    if (lane == 0) fps_idx[b * MCENT + m] = (int)(~Wlo);

    unsigned long long own = __ballot(lkb == Whi && lkn == Wlo);
    const int ol = (int)__ffsll(own) - 1;  // unique: key carries unique point id
    const float wx = rdlanef(lpx, ol);
    const float wy = rdlanef(lpy, ol);
    const float wz = rdlanef(lpz, ol);

    // prune my 2 subs (conservative bbox lower bound vs cached sub max-d)
    unsigned dm = 0u;
#pragma unroll
    for (int s2 = 0; s2 < 2; ++s2) {
      float ex = fmaxf(fmaxf(bxm[s2] - wx, wx - bxM[s2]), 0.0f);
      float ey = fmaxf(fmaxf(bym[s2] - wy, wy - byM[s2]), 0.0f);
      float ez = fmaxf(fmaxf(bzm[s2] - wz, wz - bzM[s2]), 0.0f);
      float lb = (ex * ex + ey * ey + ez * ez) * 0.999f;
      if (lb < __uint_as_float(skb[s2])) dm |= (1u << s2);
    }

    // cooperative update: one dirty sub at a time, all 64 lanes, 2 pts each
    unsigned long long anyb = __ballot(dm != 0u);
    while (anyb) {
      const int L = (int)__ffsll(anyb) - 1;           // owner lane (uniform)
      const unsigned f = (unsigned)rdlane((int)dm, L);
      const int sl = (f & 1u) ? 0 : 1;                // its dirty local sub
      const int Ssub = L * 2 + sl;                    // global sub id (uniform)
      const int pt = Ssub * 128 + lane;               // pt % 64 == lane: own dL
      float4 v0 = Sb[pt];
      float4 v1 = Sb[pt + 64];
      float n0 = fminf(dL[pt],      d2e(v0.x, v0.y, v0.z, wx, wy, wz));
      float n1 = fminf(dL[pt + 64], d2e(v1.x, v1.y, v1.z, wx, wy, wz));
      dL[pt] = n0;
      dL[pt + 64] = n1;
      unsigned c0b = __float_as_uint(n0), c0n = ~(unsigned)__float_as_int(v0.w);
      unsigned c1b = __float_as_uint(n1), c1n = ~(unsigned)__float_as_int(v1.w);
      bool gg = (c1b > c0b) || (c1b == c0b && c1n > c0n);
      unsigned cb = gg ? c1b : c0b, cn = gg ? c1n : c0n;
      float cx = gg ? v1.x : v0.x;
      float cy = gg ? v1.y : v0.y;
      float cz = gg ? v1.z : v0.z;
      unsigned b2 = cb, n2 = cn;
      DPP_LEXMAX_FULL(b2, n2);
      const unsigned nhi = (unsigned)rdlane((int)b2, 63);
      const unsigned nlo = (unsigned)rdlane((int)n2, 63);
      unsigned long long mmk = __ballot(cb == nhi && cn == nlo);
      const int fl = (int)__ffsll(mmk) - 1;
      const float nx = rdlanef(cx, fl);
      const float ny = rdlanef(cy, fl);
      const float nz = rdlanef(cz, fl);
      if (lane == L) {
        skb[sl] = nhi; skn[sl] = nlo;
        spx[sl] = nx; spy[sl] = ny; spz[sl] = nz;
        dm &= ~(1u << sl);
      }
      anyb = __ballot(dm != 0u);
    }
  }
}

// ------------- Kernel 2: ball query + K-smallest selection (1 wave/centroid) --
__global__ __launch_bounds__(256) void ballq_kernel(const float* __restrict__ pos,
                                                    const int* __restrict__ fps_idx,
                                                    int* __restrict__ nbr,
                                                    float* __restrict__ out_pc,
                                                    float* __restrict__ out_batch) {
  const int wave = threadIdx.x >> 6;
  const int lane = threadIdx.x & 63;
  const int c = blockIdx.x * 4 + wave;   // global centroid id
  const int b = c >> 12;                 // 4096 centroids per cloud
  const float* P = pos + (size_t)b * NPTS * 3;

  const int ci = fps_idx[c];
  const float cx = P[3 * ci + 0];
  const float cy = P[3 * ci + 1];
  const float cz = P[3 * ci + 2];
  if (lane == 0) {
    out_pc[3 * c + 0] = cx;
    out_pc[3 * c + 1] = cy;
    out_pc[3 * c + 2] = cz;
    out_batch[c] = (float)b;
  }

  __shared__ unsigned long long list[4][1024];
  __shared__ int cnt[4];
  if (lane == 0) cnt[wave] = 0;

  for (int i = lane; i < NPTS; i += 64) {
    const float qx = P[3 * i + 0];
    const float qy = P[3 * i + 1];
    const float qz = P[3 * i + 2];
    const float dd = d2e(cx, cy, cz, qx, qy, qz);
    if (dd <= R2CUT) {
      int p = atomicAdd(&cnt[wave], 1);
      if (p < 1024)
        list[wave][p] = ((unsigned long long)__float_as_uint(dd) << 32)
                      | (unsigned long long)(unsigned)i;
    }
  }
  __syncthreads();

  int n = cnt[wave];
  if (n > 1024) n = 1024;

  unsigned long long loc[16];
#pragma unroll
  for (int k = 0; k < 16; ++k) {
    int i = lane + k * 64;
    loc[k] = (i < n) ? list[wave][i] : ~0ULL;
  }
  unsigned long long mv = loc[0];
#pragma unroll
  for (int k = 1; k < 16; ++k)
    if (loc[k] < mv) mv = loc[k];

  int myout = -1;
  for (int s = 0; s < 64; ++s) {
    unsigned long long wmin = mv;
#pragma unroll
    for (int off = 32; off >= 1; off >>= 1) {
      unsigned long long o = __shfl_xor(wmin, off);
      if (o < wmin) wmin = o;
    }
    if (lane == s) myout = (wmin == ~0ULL) ? -1 : (int)(unsigned)wmin;
    if (mv == wmin && wmin != ~0ULL) {
#pragma unroll
      for (int k = 0; k < 16; ++k)
        if (loc[k] == wmin) loc[k] = ~0ULL;
      mv = loc[0];
#pragma unroll
      for (int k = 1; k < 16; ++k)
        if (loc[k] < mv) mv = loc[k];
    }
  }
  nbr[c * KNBR + lane] = myout;
}

// ------------- Kernel 3: MLP (35->64 relu ->128) + masked max-pool ----------
__global__ __launch_bounds__(256) void mlp_kernel(const float* __restrict__ pos,
                                                  const float* __restrict__ x,
                                                  const int* __restrict__ fps_idx,
                                                  const int* __restrict__ nbr,
                                                  const float* __restrict__ W1,
                                                  const float* __restrict__ b1,
                                                  const float* __restrict__ W2,
                                                  const float* __restrict__ b2,
                                                  float* __restrict__ out) {
  const int c = blockIdx.x;
  const int b = c >> 12;
  const float* P = pos + (size_t)b * NPTS * 3;
  const float* X = x + (size_t)b * NPTS * FDIM;

  __shared__ float W1s[35 * 64];
  __shared__ float W2s[64 * 128];
  __shared__ float b1s[64];
  __shared__ float b2s[128];
  __shared__ float h1s[64][64];
  __shared__ float pmax[2][128];
  __shared__ int validk[64];

  const int tid = threadIdx.x;
  for (int i = tid; i < 35 * 64; i += 256) W1s[i] = W1[i];
  for (int i = tid; i < 64 * 128; i += 256) W2s[i] = W2[i];
  if (tid < 64) b1s[tid] = b1[tid];
  else if (tid < 192) b2s[tid - 64] = b2[tid - 64];

  const int ci = fps_idx[c];
  const float c5x = P[3 * ci + 0] / 0.2f;  // faithful: pos_i / r
  const float c5y = P[3 * ci + 1] / 0.2f;
  const float c5z = P[3 * ci + 2] / 0.2f;

  const int k = tid >> 2, q = tid & 3;
  const int nk = nbr[c * KNBR + k];
  if (q == 0) validk[k] = (nk >= 0) ? 1 : 0;
  const int nkc = (nk < 0) ? 0 : nk;

  float msg[35];
  const float4* Xr = (const float4*)(X + (size_t)nkc * FDIM);
#pragma unroll
  for (int i4 = 0; i4 < 8; ++i4) {
    float4 v = Xr[i4];
    msg[i4 * 4 + 0] = v.x; msg[i4 * 4 + 1] = v.y;
    msg[i4 * 4 + 2] = v.z; msg[i4 * 4 + 3] = v.w;
  }
  msg[32] = P[3 * nkc + 0] - c5x;
  msg[33] = P[3 * nkc + 1] - c5y;
  msg[34] = P[3 * nkc + 2] - c5z;

  __syncthreads();

  float acc[16];
#pragma unroll
  for (int h = 0; h < 16; ++h) acc[h] = b1s[q * 16 + h];
#pragma unroll
  for (int i = 0; i < 35; ++i) {
    const float m = msg[i];
    const float4* wrow = (const float4*)&W1s[i * 64 + q * 16];
#pragma unroll
    for (int j4 = 0; j4 < 4; ++j4) {
      float4 w = wrow[j4];
      acc[j4 * 4 + 0] += m * w.x;
      acc[j4 * 4 + 1] += m * w.y;
      acc[j4 * 4 + 2] += m * w.z;
      acc[j4 * 4 + 3] += m * w.w;
    }
  }
#pragma unroll
  for (int h = 0; h < 16; ++h) h1s[k][q * 16 + h] = fmaxf(acc[h], 0.0f);
  __syncthreads();

  const int ch = tid & 127, half = tid >> 7;
  float w2r[64];
#pragma unroll
  for (int i = 0; i < 64; ++i) w2r[i] = W2s[i * 128 + ch];

  float mx = -INFINITY;
  for (int k2 = half * 32; k2 < half * 32 + 32; ++k2) {
    if (!validk[k2]) continue;
    float s = b2s[ch];
    const float4* hr = (const float4*)h1s[k2];
#pragma unroll
    for (int i4 = 0; i4 < 16; ++i4) {
      float4 h4 = hr[i4];
      s += h4.x * w2r[i4 * 4 + 0] + h4.y * w2r[i4 * 4 + 1]
         + h4.z * w2r[i4 * 4 + 2] + h4.w * w2r[i4 * 4 + 3];
    }
    mx = fmaxf(mx, s);
  }
  pmax[half][ch] = mx;
  __syncthreads();

  if (tid < 128) {
    float m2 = fmaxf(pmax[0][tid], pmax[1][tid]);
    out[(size_t)c * CODIM + tid] = (m2 > -INFINITY) ? m2 : 0.0f;
  }
}

extern "C" void kernel_launch(void* const* d_in, const int* in_sizes, int n_in,
                              void* d_out, int out_size, void* d_ws, size_t ws_size,
                              hipStream_t stream) {
  const float* x   = (const float*)d_in[0];
  const float* pos = (const float*)d_in[1];
  const float* W1  = (const float*)d_in[3];
  const float* b1  = (const float*)d_in[4];
  const float* W2  = (const float*)d_in[5];
  const float* b2  = (const float*)d_in[6];
  float* out = (float*)d_out;

  int* fps_idx = (int*)d_ws;                       // B*M ints = 32 KiB
  char* region = (char*)d_ws + (size_t)BCLD * MCENT * 4;  // 2 MiB region
  int* nbr = (int*)region;                         // B*M*K ints (ballq/mlp)
  // fps scratch aliases the nbr region (fps completes before ballq writes):
  float4* S = (float4*)region;                     // B*N float4 = 512 KiB
  unsigned* umeta = (unsigned*)(region + 524288);  // 2 x 256 u32 = 2 KiB
  float* fmeta = (float*)(region + 524288 + 2048); // 9 x 256 f32 = 9 KiB

  float* out_pc    = out + (size_t)BCLD * MCENT * CODIM;
  float* out_batch = out_pc + (size_t)BCLD * MCENT * 3;

  hipLaunchKernelGGL(sort_kernel, dim3(BCLD), dim3(1024), 0, stream,
                     pos, S, umeta, fmeta);
  hipLaunchKernelGGL(fps_wave, dim3(BCLD), dim3(64), 0, stream,
                     pos, fps_idx, S, umeta, fmeta);
  hipLaunchKernelGGL(ballq_kernel, dim3(BCLD * MCENT / 4), dim3(256), 0, stream,
                     pos, fps_idx, nbr, out_pc, out_batch);
  hipLaunchKernelGGL(mlp_kernel, dim3(BCLD * MCENT), dim3(256), 0, stream,
                     pos, x, fps_idx, nbr, W1, b1, W2, b2, out);
}